// Round 1
// 2218.677 us; speedup vs baseline: 1.9288x; 1.9288x over previous
//
#include <hip/hip_runtime.h>
#include <cstdint>
#include <cstddef>

typedef __attribute__((ext_vector_type(8))) short short8;
typedef __attribute__((ext_vector_type(4))) short short4v;
typedef __attribute__((ext_vector_type(4))) float float4v;

typedef __attribute__((address_space(3))) uint32_t lds_u32;
typedef const __attribute__((address_space(1))) uint32_t gl_u32;

__device__ __forceinline__ short f2bf(float f) {
    union { float f; uint32_t u; } v; v.f = f;
    uint32_t r = v.u + 0x7fffu + ((v.u >> 16) & 1u);
    return (short)(r >> 16);
}
__device__ __forceinline__ float bf2f(short s) {
    union { uint32_t u; float f; } v; v.u = ((uint32_t)(uint16_t)s) << 16;
    return v.f;
}
__device__ __forceinline__ float sigmoidf_(float z) {
    return 1.0f / (1.0f + __expf(-z));
}

// ---------------------------------------------------------------------------
// Prep: x (32768x1024 f32) -> bf16 into Xcat[:, 0:1024] (row stride 1280)
// ---------------------------------------------------------------------------
__global__ __launch_bounds__(256) void xconvert_kernel(const float* __restrict__ x,
                                                       short* __restrict__ Xcat) {
    size_t i = ((size_t)blockIdx.x * 256 + threadIdx.x) * 4;
    size_t r = i >> 10, c = i & 1023;
    float4v v = *(const float4v*)(x + i);
    short4v o;
#pragma unroll
    for (int j = 0; j < 4; ++j) o[j] = f2bf(v[j]);
    *(short4v*)(Xcat + r * 1280 + c) = o;
}

// ---------------------------------------------------------------------------
// Prep: W3b = bf16([Wi; Wf[:, :1024]; Wu[:, :1024]]) (768x1024)
//       Wob = bf16(Wo) (1024x1280)
// ---------------------------------------------------------------------------
__global__ __launch_bounds__(256) void wconvert_kernel(const float* __restrict__ Wi,
                                                       const float* __restrict__ Wf,
                                                       const float* __restrict__ Wu,
                                                       const float* __restrict__ Wo,
                                                       short* __restrict__ W3b,
                                                       short* __restrict__ Wob) {
    int i = blockIdx.x * 256 + threadIdx.x;
    if (i < 768 * 1024) {
        int n = i >> 10, k = i & 1023;
        const float* src = (n < 256) ? (Wi + (size_t)n * 1024 + k)
                         : (n < 512) ? (Wf + (size_t)(n - 256) * 1280 + k)
                                     : (Wu + (size_t)(n - 512) * 1280 + k);
        W3b[i] = f2bf(*src);
    } else {
        int j = i - 768 * 1024;   // 0 .. 1024*1280-1
        Wob[j] = f2bf(Wo[j]);
    }
}

// ---------------------------------------------------------------------------
// Tiled bf16 MFMA GEMM: C[gr][gc] = sum_k A[gr][k]*B[gc][k]
// 128x128 tile, BK=32, 256 threads (4 waves, 2x2), global_load_lds staging.
// EPI=1: bias + silu(first 256 cols), bf16 out to xmfu[gr][gc] ([b*2048+t][768])
// EPI=2: + bo[gc] + x[gr][gc] residual, fp32 out to d_out
// ---------------------------------------------------------------------------
template <int EPI>
__global__ __launch_bounds__(256) void gemm_bt(const short* __restrict__ A,
                                               const short* __restrict__ Bmat,
                                               const int K, const int lda,
                                               const float* __restrict__ bias1,
                                               const float* __restrict__ bias2,
                                               const float* __restrict__ bias3,
                                               const float* __restrict__ xres,
                                               float* __restrict__ outf,
                                               short* __restrict__ outb) {
    __shared__ __align__(16) short As[4096];
    __shared__ __align__(16) short Bs[4096];

    const int tid = threadIdx.x;
    const int lane = tid & 63;
    const int wv = tid >> 6;
    const int wm = wv >> 1, wn = wv & 1;
    const int row15 = lane & 15;
    const int q = lane >> 4;
    const int tileM = blockIdx.x * 128;
    const int tileN = blockIdx.y * 128;

    float4v acc[4][4];
#pragma unroll
    for (int i = 0; i < 4; ++i)
#pragma unroll
        for (int j = 0; j < 4; ++j) acc[i][j] = {0.f, 0.f, 0.f, 0.f};

    const short* aG = A + (size_t)(tileM + (tid >> 2)) * lda + (tid & 3) * 8;
    const short* bG = Bmat + (size_t)(tileN + (tid >> 2)) * K + (tid & 3) * 8;
    const size_t aStep = (size_t)64 * lda;
    const size_t bStep = (size_t)64 * K;

    lds_u32* AsL = (lds_u32*)As;
    lds_u32* BsL = (lds_u32*)Bs;
    const int base1 = wv * 256;
    const int base2 = 1024 + wv * 256;

    for (int kt = 0; kt < K; kt += 32) {
        __builtin_amdgcn_global_load_lds((gl_u32*)aG,           AsL + base1, 16, 0, 0);
        __builtin_amdgcn_global_load_lds((gl_u32*)(aG + aStep), AsL + base2, 16, 0, 0);
        __builtin_amdgcn_global_load_lds((gl_u32*)bG,           BsL + base1, 16, 0, 0);
        __builtin_amdgcn_global_load_lds((gl_u32*)(bG + bStep), BsL + base2, 16, 0, 0);
        aG += 32; bG += 32;
        __syncthreads();

        short8 af[4], bf8[4];
#pragma unroll
        for (int mt = 0; mt < 4; ++mt)
            af[mt] = *(const short8*)(As + (wm * 64 + mt * 16 + row15) * 32 + q * 8);
#pragma unroll
        for (int nt = 0; nt < 4; ++nt)
            bf8[nt] = *(const short8*)(Bs + (wn * 64 + nt * 16 + row15) * 32 + q * 8);
#pragma unroll
        for (int mt = 0; mt < 4; ++mt)
#pragma unroll
            for (int nt = 0; nt < 4; ++nt)
                acc[mt][nt] = __builtin_amdgcn_mfma_f32_16x16x32_bf16(af[mt], bf8[nt], acc[mt][nt], 0, 0, 0);
        __syncthreads();
    }

#pragma unroll
    for (int mt = 0; mt < 4; ++mt) {
#pragma unroll
        for (int nt = 0; nt < 4; ++nt) {
#pragma unroll
            for (int r = 0; r < 4; ++r) {
                const int gr = tileM + wm * 64 + mt * 16 + q * 4 + r;
                const int gc = tileN + wn * 64 + nt * 16 + row15;
                float v = acc[mt][nt][r];
                if (EPI == 1) {
                    float bias = (gc < 256) ? bias1[gc] : (gc < 512) ? bias2[gc - 256] : bias3[gc - 512];
                    float z = v + bias;
                    if (gc < 256) z = z * sigmoidf_(z);   // silu for xm
                    outb[(size_t)gr * 768 + gc] = f2bf(z);
                } else {
                    const size_t idx = (size_t)gr * 1024 + gc;
                    outf[idx] = v + bias1[gc] + xres[idx];
                }
            }
        }
    }
}

// ---------------------------------------------------------------------------
// Sequential scan, ONE WORKGROUP PER BATCH (grid=16, 512 threads = 8 waves).
// Wave w: sel=w>>2 (0=f/Wf, 1=u/Wu), cols n0=(w&3)*64 .. +63 (4 N-tiles).
// h lives bf16 in a tiny LDS A-frag buffer (only MFMA row 0 real; A-reads
// exec-predicated to 4 lanes, slot-swizzled so reads AND scatter-writes are
// bank-conflict-free). Raw z -> fuz LDS; 256 update threads (waves 0-3) do
// bias+sigmoid+h-update. Loader waves 4-7 double-buffer 8-step blocks of
// xm/xf/xu into LDS via global_load_lds (their vmcnt queue is pure, so one
// vmcnt(0) per 8 steps). Raw s_barrier + lgkmcnt fences: H-stores and block
// loads stay in flight across barriers (no vmcnt(0)-drain per step).
// ---------------------------------------------------------------------------
__global__ __launch_bounds__(512) void scan_kernel(const float* __restrict__ Wfp,
                                                   const float* __restrict__ Wup,
                                                   const short* __restrict__ xmfu,
                                                   short* __restrict__ Xcat,
                                                   float* __restrict__ hfinal) {
    __shared__ __align__(16) short hb[4096];        // h bf16, swizzled A-frag slots
    __shared__ __align__(16) short xstage[2][6144]; // 8 steps x [xm|xf|xu], dbuf
    __shared__ __align__(16) float fuz[512];        // raw MFMA z: f [0,256), u [256,512)

    const int tid = threadIdx.x;
    const int lane = tid & 63;
    const int w = tid >> 6;          // 0..7
    const int sel = w >> 2;          // 0=f, 1=u
    const int n0 = (w & 3) * 64;
    const int row15 = lane & 15;
    const int q = lane >> 4;
    const int b = blockIdx.x;

    const short* xm_b = xmfu + (size_t)b * 1572864;   // [b][2048][768]

    for (int i = tid; i < 4096; i += 512) hb[i] = 0;

    // B-fragments: B[k][n] = WH[n][1024+k]; lane holds n = n0+nt*16+row15,
    // k = ks*32 + q*8 + j. 32 short8 (128 regs) held for the whole scan.
    const float* WH = sel ? Wup : Wfp;
    short8 bfrag[8][4];
#pragma unroll
    for (int ks = 0; ks < 8; ++ks)
#pragma unroll
        for (int nt = 0; nt < 4; ++nt) {
            const float* src = WH + (size_t)(n0 + nt * 16 + row15) * 1280 + 1024 + ks * 32 + q * 8;
            float4v v0 = *(const float4v*)(src);
            float4v v1 = *(const float4v*)(src + 4);
            short8 v;
#pragma unroll
            for (int j = 0; j < 4; ++j) { v[j] = f2bf(v0[j]); v[j + 4] = f2bf(v1[j]); }
            bfrag[ks][nt] = v;
        }

    // loaders: threads 256..511 stage 8-step blocks (12288 B) of xmfu
    const bool isLoader = (tid >= 256);
    const int lw = (tid - 256) >> 6;                  // loader wave 0..3
    lds_u32* xl = (lds_u32*)(&xstage[0][0]);

    if (isLoader) {
#pragma unroll
        for (int i = 0; i < 3; ++i)
            __builtin_amdgcn_global_load_lds((gl_u32*)(xm_b + i * 2048 + lw * 512 + lane * 8),
                                             xl + (i * 1024 + lw * 256), 16, 0, 0);
        __builtin_amdgcn_sched_barrier(0);
        asm volatile("s_waitcnt vmcnt(0)" ::: "memory");
        __builtin_amdgcn_sched_barrier(0);
    }
    __builtin_amdgcn_sched_barrier(0);
    asm volatile("s_waitcnt lgkmcnt(0)" ::: "memory");
    __builtin_amdgcn_sched_barrier(0);
    __builtin_amdgcn_s_barrier();
    __builtin_amdgcn_sched_barrier(0);

    float hreg = 0.f;
    const int m = tid;               // update thread's h index (valid tid<256)
    const int mks = m >> 5, mq = (m >> 3) & 3, mj = m & 7;
    const int hslot = mks * 512 + (mq * 18 + mks) * 8 + mj;   // swizzled slot
    short* Xout = Xcat + (size_t)b * 2048 * 1280 + 1024 + m;

    short8 afr = {0, 0, 0, 0, 0, 0, 0, 0};   // A-frag; stays 0 in rows 1-15

#pragma unroll 1
    for (int j = 0; j < 256; ++j) {
        const int buf = j & 1;
        if (isLoader && (j + 1 < 256)) {
            const short* src = xm_b + (size_t)(j + 1) * 6144;
#pragma unroll
            for (int i = 0; i < 3; ++i)
                __builtin_amdgcn_global_load_lds((gl_u32*)(src + i * 2048 + lw * 512 + lane * 8),
                                                 xl + ((buf ^ 1) * 3072 + i * 1024 + lw * 256), 16, 0, 0);
        }
        const short* xs = &xstage[buf][0];
#pragma unroll
        for (int s = 0; s < 8; ++s) {
            // ---- phase 1: logits (all waves). A-read: 4 lanes only. ----
            float4v a0 = {0.f, 0.f, 0.f, 0.f}, a1 = {0.f, 0.f, 0.f, 0.f};
            float4v a2 = {0.f, 0.f, 0.f, 0.f}, a3 = {0.f, 0.f, 0.f, 0.f};
#pragma unroll
            for (int ks = 0; ks < 8; ++ks) {
                if (row15 == 0)
                    afr = *(const short8*)(hb + ks * 512 + (q * 18 + ks) * 8);
                a0 = __builtin_amdgcn_mfma_f32_16x16x32_bf16(afr, bfrag[ks][0], a0, 0, 0, 0);
                a1 = __builtin_amdgcn_mfma_f32_16x16x32_bf16(afr, bfrag[ks][1], a1, 0, 0, 0);
                a2 = __builtin_amdgcn_mfma_f32_16x16x32_bf16(afr, bfrag[ks][2], a2, 0, 0, 0);
                a3 = __builtin_amdgcn_mfma_f32_16x16x32_bf16(afr, bfrag[ks][3], a3, 0, 0, 0);
            }
            // row 0 (the real batch) = lanes 0..15, reg 0 of each acc
            if (lane < 16) {
                float4v v = {a0[0], a1[0], a2[0], a3[0]};
                *(float4v*)(fuz + sel * 256 + (w & 3) * 64 + lane * 4) = v;
            }
            __builtin_amdgcn_sched_barrier(0);
            asm volatile("s_waitcnt lgkmcnt(0)" ::: "memory");
            __builtin_amdgcn_sched_barrier(0);
            __builtin_amdgcn_s_barrier();
            __builtin_amdgcn_sched_barrier(0);
            // ---- phase 2: bias + sigmoid + h update (waves 0-3) ----
            if (tid < 256) {
                const int fidx = (m >> 6) * 64 + (m & 15) * 4 + ((m >> 4) & 3);
                const float zf = fuz[fidx];
                const float zu = fuz[256 + fidx];
                const float zbf = bf2f(xs[s * 768 + 256 + m]);
                const float zbu = bf2f(xs[s * 768 + 512 + m]);
                const float xmv = bf2f(xs[s * 768 + m]);
                const float f = sigmoidf_(zf + zbf);
                const float u = sigmoidf_(zu + zbu);
                const float hn = f * hreg + u * xmv;
                hreg = hn;
                const short hnb = f2bf(hn);
                hb[hslot] = hnb;
                Xout[(size_t)(j * 8 + s) * 1280] = hnb;   // H -> Xcat, in flight
            }
            if (s == 7 && isLoader) {   // next block's loads must be in LDS
                __builtin_amdgcn_sched_barrier(0);
                asm volatile("s_waitcnt vmcnt(0)" ::: "memory");
                __builtin_amdgcn_sched_barrier(0);
            }
            __builtin_amdgcn_sched_barrier(0);
            asm volatile("s_waitcnt lgkmcnt(0)" ::: "memory");
            __builtin_amdgcn_sched_barrier(0);
            __builtin_amdgcn_s_barrier();
            __builtin_amdgcn_sched_barrier(0);
        }
    }
    if (tid < 256) hfinal[b * 256 + m] = hreg;
}

// ---------------------------------------------------------------------------
extern "C" void kernel_launch(void* const* d_in, const int* in_sizes, int n_in,
                              void* d_out, int out_size, void* d_ws, size_t ws_size,
                              hipStream_t stream) {
    const float* x  = (const float*)d_in[0];
    const float* Wi = (const float*)d_in[1];
    const float* bi = (const float*)d_in[2];
    const float* Wf = (const float*)d_in[3];
    const float* bf = (const float*)d_in[4];
    const float* Wu = (const float*)d_in[5];
    const float* bu = (const float*)d_in[6];
    const float* Wo = (const float*)d_in[7];
    const float* bo = (const float*)d_in[8];
    float* out = (float*)d_out;   // 33554432 outs + 4096 h_final

    char* ws = (char*)d_ws;
    short* Xcat = (short*)ws;                                  // 32768*1280*2 = 83,886,080 B
    short* xmfu = (short*)(ws + 83886080ULL);                  // [b][t][768]: 50,331,648 B
    short* W3b  = (short*)(ws + 83886080ULL + 50331648ULL);    // 768*1024*2
    short* Wob  = (short*)(ws + 83886080ULL + 50331648ULL + 1572864ULL); // 1024*1280*2

    xconvert_kernel<<<dim3(32768), dim3(256), 0, stream>>>(x, Xcat);
    wconvert_kernel<<<dim3(8192), dim3(256), 0, stream>>>(Wi, Wf, Wu, Wo, W3b, Wob);
    // xm/xf/xu: (32768 x 768) = Xcat[:, :1024] @ W3b^T (+bias, silu on xm)
    gemm_bt<1><<<dim3(256, 6), dim3(256), 0, stream>>>(Xcat, W3b, 1024, 1280,
                                                       bi, bf, bu, nullptr, nullptr, xmfu);
    // sequential recurrence: 16 independent batch workgroups
    scan_kernel<<<dim3(16), dim3(512), 0, stream>>>(Wf, Wu, xmfu, Xcat, out + 33554432);
    // out = x + Xcat @ Wo^T + bo   (covers x@Wo[:,:d]^T + H@WoH^T)
    gemm_bt<2><<<dim3(256, 8), dim3(256), 0, stream>>>(Xcat, Wob, 1280, 1280,
                                                       bo, nullptr, nullptr, x, out, nullptr);
}